// Round 7
// baseline (444.948 us; speedup 1.0000x reference)
//
#include <hip/hip_runtime.h>
#include <math.h>

using short8 = __attribute__((ext_vector_type(8))) short;
using f32x4  = __attribute__((ext_vector_type(4))) float;

__device__ __forceinline__ ushort f2bf(float f) {
    union { float f; uint u; } c; c.f = f;
    uint u = c.u;
    uint r = (u + 0x7FFFu + ((u >> 16) & 1u)) >> 16;
    return (ushort)r;
}
__device__ __forceinline__ float bf2f(ushort h) {
    union { uint u; float f; } c; c.u = ((uint)h) << 16;
    return c.f;
}
// pack 4 floats -> 4 fp8 e4m3 (OCP on gfx950) in one dword
__device__ __forceinline__ uint pk4_fp8(float a, float b, float c, float d) {
    int v = __builtin_amdgcn_cvt_pk_fp8_f32(a, b, 0, false);
    v = __builtin_amdgcn_cvt_pk_fp8_f32(c, d, v, true);
    return (uint)v;
}
__device__ __forceinline__ unsigned char f2fp8(float x) {
    return (unsigned char)__builtin_amdgcn_cvt_pk_fp8_f32(x, 0.f, 0, false);
}

// async global->LDS, 16 bytes per lane; lds dest = wave-uniform base + lane*16
__device__ __forceinline__ void gload16(const void* g, void* l) {
    __builtin_amdgcn_global_load_lds(
        (const __attribute__((address_space(1))) unsigned int*)g,
        (__attribute__((address_space(3))) unsigned int*)l,
        16, 0, 0);
}

// ---------------- weight prep: fp32 -> bf16, fold softmax scale into Wq/bq ---
__global__ __launch_bounds__(256) void prep_weights(
    const float* __restrict__ wq, const float* __restrict__ bq,
    const float* __restrict__ wk, const float* __restrict__ bk,
    const float* __restrict__ wv, const float* __restrict__ wo,
    ushort* __restrict__ Wqk, ushort* __restrict__ Wv, ushort* __restrict__ Wo,
    float* __restrict__ bqk, float scale)
{
    int idx = blockIdx.x * 256 + threadIdx.x;
    if (idx < 1024 * 512) {
        float v = (idx < 262144) ? wq[idx] * scale : wk[idx - 262144];
        Wqk[idx] = f2bf(v);
    }
    if (idx < 262144) {
        Wv[idx] = f2bf(wv[idx]);
        Wo[idx] = f2bf(wo[idx]);
    }
    if (idx < 1024) bqk[idx] = (idx < 512) ? bq[idx] * scale : bk[idx - 512];
}

// ------- GroupNorm: [4,512,4096] fp32 -> bf16 TRANSPOSED hn_t[b][hw][c] -----
__global__ __launch_bounds__(256) void gn_kernel(
    const float* __restrict__ x, const float* __restrict__ gamma,
    const float* __restrict__ beta, ushort* __restrict__ hnt)
{
    int blk = blockIdx.x;          // b*32 + g, 128 total
    int b = blk >> 5, g = blk & 31;
    const float* xp = x + (size_t)blk * 65536;   // group chunk: 16 ch * 4096
    int tid = threadIdx.x;

    float s = 0.f, sq = 0.f;
    for (int i = tid * 4; i < 65536; i += 1024) {
        float4 v = *(const float4*)&xp[i];
        s  += v.x + v.y + v.z + v.w;
        sq += v.x * v.x + v.y * v.y + v.z * v.z + v.w * v.w;
    }
    #pragma unroll
    for (int off = 32; off; off >>= 1) {
        s  += __shfl_xor(s,  off, 64);
        sq += __shfl_xor(sq, off, 64);
    }
    __shared__ float red[8];
    if ((tid & 63) == 0) { red[(tid >> 6) * 2] = s; red[(tid >> 6) * 2 + 1] = sq; }
    __syncthreads();
    float ts = red[0] + red[2] + red[4] + red[6];
    float tq = red[1] + red[3] + red[5] + red[7];
    float mean = ts * (1.f / 65536.f);
    float var  = tq * (1.f / 65536.f) - mean * mean;
    float rstd = rsqrtf(var + 1e-6f);

    float a[16], c[16];
    #pragma unroll
    for (int ch = 0; ch < 16; ++ch) {
        float ga = gamma[g * 16 + ch], be = beta[g * 16 + ch];
        a[ch] = rstd * ga; c[ch] = be - mean * a[ch];
    }

    __shared__ ushort ls[16][256];
    for (int tile = 0; tile < 16; ++tile) {
        int i0 = tile * 256;
        __syncthreads();
        #pragma unroll
        for (int ch = 0; ch < 16; ++ch)
            ls[ch][tid] = f2bf(xp[ch * 4096 + i0 + tid] * a[ch] + c[ch]);
        __syncthreads();
        ushort t[16];
        #pragma unroll
        for (int ch = 0; ch < 16; ++ch) t[ch] = ls[ch][tid];
        size_t dst = ((size_t)b * 4096 + i0 + tid) * 512 + g * 16;
        *(uint4*)&hnt[dst]     = *(const uint4*)&t[0];
        *(uint4*)&hnt[dst + 8] = *(const uint4*)&t[8];
    }
}

// ---- softmax over rows of 4096: bf16 S in -> fp8 (x256) P8 out -------------
__global__ __launch_bounds__(256) void softmax_kernel(
    const ushort* __restrict__ S, unsigned char* __restrict__ P8)
{
    size_t row = blockIdx.x;
    const ushort* p = S + row * 4096;
    int tid = threadIdx.x;

    ushort tmp[16];
    *(uint4*)&tmp[0] = *(const uint4*)&p[tid * 16];
    *(uint4*)&tmp[8] = *(const uint4*)&p[tid * 16 + 8];
    float v[16];
    float mx = -1e30f;
    #pragma unroll
    for (int j = 0; j < 16; ++j) { v[j] = bf2f(tmp[j]); mx = fmaxf(mx, v[j]); }
    #pragma unroll
    for (int off = 32; off; off >>= 1) mx = fmaxf(mx, __shfl_xor(mx, off, 64));
    __shared__ float ls[8];
    if ((tid & 63) == 0) ls[tid >> 6] = mx;
    __syncthreads();
    float m4 = fmaxf(fmaxf(ls[0], ls[1]), fmaxf(ls[2], ls[3]));
    float sum = 0.f;
    #pragma unroll
    for (int j = 0; j < 16; ++j) { v[j] = __expf(v[j] - m4); sum += v[j]; }
    #pragma unroll
    for (int off = 32; off; off >>= 1) sum += __shfl_xor(sum, off, 64);
    if ((tid & 63) == 0) ls[4 + (tid >> 6)] = sum;
    __syncthreads();
    // scale by 256 so diffuse probs (~2.4e-4) clear e4m3's subnormal floor
    float inv = 256.0f / (ls[4] + ls[5] + ls[6] + ls[7]);
    uint4 o;
    o.x = pk4_fp8(v[0] * inv,  v[1] * inv,  v[2] * inv,  v[3] * inv);
    o.y = pk4_fp8(v[4] * inv,  v[5] * inv,  v[6] * inv,  v[7] * inv);
    o.z = pk4_fp8(v[8] * inv,  v[9] * inv,  v[10] * inv, v[11] * inv);
    o.w = pk4_fp8(v[12] * inv, v[13] * inv, v[14] * inv, v[15] * inv);
    *(uint4*)&P8[row * 4096 + tid * 16] = o;
}

// ---- NT bf16 MFMA GEMM, 128x128 tile, BK=64 (two 32-k sub-tiles/barrier) ---
// C[m,n] = sum_k A[m,k]*B[n,k]   A: [M][K] lda, B: [N][K] ldb (both K-contig)
// OUT: 0 bf16, 1 fp32 + resid, 2 fp8-e4m3.  BIAS: 0 none, 1 row, 2 col.
template <int BIAS, int OUT>
__global__ __launch_bounds__(256, 4) void gemm_nt(
    const ushort* __restrict__ Ag, const ushort* __restrict__ Bg,
    void* __restrict__ Cv,
    const float* __restrict__ bias, const float* __restrict__ resid,
    int N, int K, int lda, int ldb,
    long sA, long sB, long sC)
{
    const int bz = blockIdx.z;
    Ag += (size_t)bz * sA;
    Bg += (size_t)bz * sB;

    const int tid  = threadIdx.x;
    const int wave = tid >> 6, lane = tid & 63;
    const int q = lane >> 4, lr = lane & 15;
    const int m0 = blockIdx.x * 128, n0 = blockIdx.y * 128;   // m on X!
    const int wm = (wave >> 1) * 64, wn = (wave & 1) * 64;

    __shared__ __align__(16) ushort As[2][128 * 32];   // 2 x 8 KB
    __shared__ __align__(16) ushort Bs[2][128 * 32];   // 2 x 8 KB

    const int srow = wave * 32 + (lane >> 2);
    const int skc  = (lane & 3) << 3;
    const size_t aoff0 = (size_t)(m0 + srow) * lda + skc;
    const size_t aoff1 = aoff0 + (size_t)16 * lda;
    const size_t boff0 = (size_t)(n0 + srow) * ldb + skc;
    const size_t boff1 = boff0 + (size_t)16 * ldb;
    const int l0 = wave * 1024, l1 = wave * 1024 + 512;   // wave-uniform bases

    f32x4 acc[4][4] = {};

    for (int kb = 0; kb < K; kb += 64) {
        __syncthreads();
        gload16(&Ag[aoff0 + kb],      &As[0][l0]);
        gload16(&Ag[aoff1 + kb],      &As[0][l1]);
        gload16(&Ag[aoff0 + kb + 32], &As[1][l0]);
        gload16(&Ag[aoff1 + kb + 32], &As[1][l1]);
        gload16(&Bg[boff0 + kb],      &Bs[0][l0]);
        gload16(&Bg[boff1 + kb],      &Bs[0][l1]);
        gload16(&Bg[boff0 + kb + 32], &Bs[1][l0]);
        gload16(&Bg[boff1 + kb + 32], &Bs[1][l1]);
        __syncthreads();

        #pragma unroll
        for (int kh = 0; kh < 2; ++kh) {
            short8 af[4], bfr[4];
            #pragma unroll
            for (int mt = 0; mt < 4; ++mt)
                af[mt] = *(const short8*)&As[kh][(wm + mt * 16 + lr) * 32 + q * 8];
            #pragma unroll
            for (int nt = 0; nt < 4; ++nt)
                bfr[nt] = *(const short8*)&Bs[kh][(wn + nt * 16 + lr) * 32 + q * 8];
            #pragma unroll
            for (int mt = 0; mt < 4; ++mt)
                #pragma unroll
                for (int nt = 0; nt < 4; ++nt)
                    acc[mt][nt] = __builtin_amdgcn_mfma_f32_16x16x32_bf16(
                        af[mt], bfr[nt], acc[mt][nt], 0, 0, 0);
        }
    }

    #pragma unroll
    for (int mt = 0; mt < 4; ++mt) {
        int rb = m0 + wm + mt * 16 + q * 4;
        #pragma unroll
        for (int nt = 0; nt < 4; ++nt) {
            int cn = n0 + wn + nt * 16 + lr;
            #pragma unroll
            for (int t = 0; t < 4; ++t) {
                int r = rb + t;
                float v = acc[mt][nt][t];
                if (BIAS == 1) v += bias[r];
                if (BIAS == 2) v += bias[cn];
                size_t o = (size_t)bz * sC + (size_t)r * N + cn;
                if (OUT == 1)      ((float*)Cv)[o] = v + resid[o];
                else if (OUT == 2) ((unsigned char*)Cv)[o] = f2fp8(v);
                else               ((ushort*)Cv)[o] = f2bf(v);
            }
        }
    }
}

// ---- PV GEMM, fp8 e4m3, 128x128 tile, BK=128 fp8 elems per barrier ---------
// Ot[i][c] = (1/256) * sum_j P8[i,j] * V8[c,j].  M=4096, N=512, K=4096.
// Two 64B-row sub-buffers per operand keep the proven conflict-free layout.
__global__ __launch_bounds__(256, 4) void gemm_pv(
    const unsigned char* __restrict__ P8, const unsigned char* __restrict__ V8,
    ushort* __restrict__ Ot)
{
    const int bz = blockIdx.z;
    const unsigned char* Ag = P8 + (size_t)bz * 16777216;   // 4096*4096
    const unsigned char* Bg = V8 + (size_t)bz * 2097152;    // 512*4096

    const int tid  = threadIdx.x;
    const int wave = tid >> 6, lane = tid & 63;
    const int q = lane >> 4, lr = lane & 15;
    const int m0 = blockIdx.x * 128, n0 = blockIdx.y * 128;  // m on X (XCD share)
    const int wm = (wave >> 1) * 64, wn = (wave & 1) * 64;

    __shared__ __align__(16) unsigned char As[2][128 * 64];  // 2 x 8 KB
    __shared__ __align__(16) unsigned char Bs[2][128 * 64];  // 2 x 8 KB

    const int srow = wave * 32 + (lane >> 2);
    const int soff = (lane & 3) << 4;               // 16-B chunk in 64-B row
    const size_t a0 = (size_t)(m0 + srow) * 4096 + soff;
    const size_t a1 = a0 + (size_t)16 * 4096;
    const size_t b0 = (size_t)(n0 + srow) * 4096 + soff;
    const size_t b1 = b0 + (size_t)16 * 4096;
    const int l0 = wave * 2048, l1 = wave * 2048 + 1024;

    f32x4 acc[4][4] = {};

    for (int kb = 0; kb < 4096; kb += 128) {
        __syncthreads();
        gload16(Ag + a0 + kb,      &As[0][l0]);
        gload16(Ag + a1 + kb,      &As[0][l1]);
        gload16(Ag + a0 + kb + 64, &As[1][l0]);
        gload16(Ag + a1 + kb + 64, &As[1][l1]);
        gload16(Bg + b0 + kb,      &Bs[0][l0]);
        gload16(Bg + b1 + kb,      &Bs[0][l1]);
        gload16(Bg + b0 + kb + 64, &Bs[1][l0]);
        gload16(Bg + b1 + kb + 64, &Bs[1][l1]);
        __syncthreads();

        #pragma unroll
        for (int kh = 0; kh < 2; ++kh) {
            #pragma unroll
            for (int kk = 0; kk < 2; ++kk) {
                long long af[4], bf[4];
                #pragma unroll
                for (int mt = 0; mt < 4; ++mt)
                    af[mt] = *(const long long*)
                        &As[kh][(wm + mt * 16 + lr) * 64 + kk * 32 + q * 8];
                #pragma unroll
                for (int nt = 0; nt < 4; ++nt)
                    bf[nt] = *(const long long*)
                        &Bs[kh][(wn + nt * 16 + lr) * 64 + kk * 32 + q * 8];
                #pragma unroll
                for (int mt = 0; mt < 4; ++mt)
                    #pragma unroll
                    for (int nt = 0; nt < 4; ++nt)
                        acc[mt][nt] = __builtin_amdgcn_mfma_f32_16x16x32_fp8_fp8(
                            af[mt], bf[nt], acc[mt][nt], 0, 0, 0);
            }
        }
    }

    #pragma unroll
    for (int mt = 0; mt < 4; ++mt) {
        int rb = m0 + wm + mt * 16 + q * 4;
        #pragma unroll
        for (int nt = 0; nt < 4; ++nt) {
            int cn = n0 + wn + nt * 16 + lr;
            #pragma unroll
            for (int t = 0; t < 4; ++t) {
                size_t o = (size_t)bz * 2097152 + (size_t)(rb + t) * 512 + cn;
                Ot[o] = f2bf(acc[mt][nt][t] * (1.f / 256.f));
            }
        }
    }
}

// ---------------- launch -----------------------------------------------------
extern "C" void kernel_launch(void* const* d_in, const int* in_sizes, int n_in,
                              void* d_out, int out_size, void* d_ws, size_t ws_size,
                              hipStream_t stream)
{
    const float* x   = (const float*)d_in[0];
    const float* gnw = (const float*)d_in[1];
    const float* gnb = (const float*)d_in[2];
    const float* wq  = (const float*)d_in[3];
    const float* bq  = (const float*)d_in[4];
    const float* wk  = (const float*)d_in[5];
    const float* bk  = (const float*)d_in[6];
    const float* wv  = (const float*)d_in[7];
    const float* bv  = (const float*)d_in[8];
    const float* wo  = (const float*)d_in[9];
    const float* bo  = (const float*)d_in[10];
    float* out = (float*)d_out;

    char* ws = (char*)d_ws;
    // ws layout with lifetime overlays (footprint ~212 MB):
    //  [0,128M)      S (bf16 scores)  -> dead after softmax; Ot overlays [0,16M)
    //  [128M,144M)   hnt              -> dead after scores
    //  [144M,176M)   QKt              -> dead after scores
    //  [128M,192M)   P8 (fp8 x256)    -> overlays hnt+QKt, written by softmax
    //  [192M,200M)   V8 (fp8)
    //  [200M+..]     weights
    ushort*        S   = (ushort*)(ws);
    ushort*        Ot  = (ushort*)(ws);                       // overlay of S
    ushort*        hnt = (ushort*)(ws + 134217728);
    ushort*        QKt = (ushort*)(ws + 150994944);
    unsigned char* P8  = (unsigned char*)(ws + 134217728);    // overlay
    unsigned char* V8  = (unsigned char*)(ws + 201326592);
    ushort*        Wqk = (ushort*)(ws + 209715200);
    ushort*        Wv  = (ushort*)(ws + 210763776);
    ushort*        Wo  = (ushort*)(ws + 211288064);
    float*         bqk = (float*) (ws + 211812352);

    const float scale = 1.0f / sqrtf(512.0f);
    const long sHW  = 512L * 4096;     // 2 M elems
    const long sQK  = 4096L * 1024;
    const long sP   = 4096L * 4096;

    prep_weights<<<2048, 256, 0, stream>>>(wq, bq, wk, bk, wv, wo,
                                           Wqk, Wv, Wo, bqk, scale);
    gn_kernel<<<128, 256, 0, stream>>>(x, gnw, gnb, hnt);

    // QKt[i][o] = hn_t[i][c] . Wqk[o][c]  (M=4096, N=1024, K=512), col-bias
    gemm_nt<2, 0><<<dim3(32, 8, 4), 256, 0, stream>>>(
        hnt, Wqk, QKt, bqk, nullptr,
        1024, 512, 512, 512, sHW, 0L, sQK);

    // V8[o][j] = fp8( Wv[o][c] . hn_t[j][c] + bv )  (M=512, N=4096, K=512)
    gemm_nt<1, 2><<<dim3(4, 32, 4), 256, 0, stream>>>(
        Wv, hnt, V8, bv, nullptr,
        4096, 512, 512, 512, 0L, sHW, sHW);

    // S[i][j] = Qt[i][c] . Kt[j][c]  (M=N=4096, K=512)
    gemm_nt<0, 0><<<dim3(32, 32, 4), 256, 0, stream>>>(
        QKt, QKt + 512, S, nullptr, nullptr,
        4096, 512, 1024, 1024, sQK, sQK, sP);

    softmax_kernel<<<16384, 256, 0, stream>>>(S, P8);

    // Ot[i][c] = (1/256) P8[i][j] . V8[c][j]  (fp8 MFMA, BK=128)
    gemm_pv<<<dim3(32, 4, 4), 256, 0, stream>>>(P8, V8, Ot);

    // out[o][i] = x + Wo[o][c] . Ot[i][c] + bo  (M=512, N=4096, K=512), fp32
    gemm_nt<1, 1><<<dim3(4, 32, 4), 256, 0, stream>>>(
        Wo, Ot, out, bo, x,
        4096, 512, 512, 512, 0L, sHW, sHW);
}

// Round 8
// 367.381 us; speedup vs baseline: 1.2111x; 1.2111x over previous
//
#include <hip/hip_runtime.h>
#include <math.h>

using short8 = __attribute__((ext_vector_type(8))) short;
using f32x4  = __attribute__((ext_vector_type(4))) float;
using llong2 = __attribute__((ext_vector_type(2))) long long;

__device__ __forceinline__ ushort f2bf(float f) {
    union { float f; uint u; } c; c.f = f;
    uint u = c.u;
    uint r = (u + 0x7FFFu + ((u >> 16) & 1u)) >> 16;
    return (ushort)r;
}
__device__ __forceinline__ float bf2f(ushort h) {
    union { uint u; float f; } c; c.u = ((uint)h) << 16;
    return c.f;
}
// pack 4 floats -> 4 fp8 e4m3 (OCP on gfx950) in one dword
__device__ __forceinline__ uint pk4_fp8(float a, float b, float c, float d) {
    int v = __builtin_amdgcn_cvt_pk_fp8_f32(a, b, 0, false);
    v = __builtin_amdgcn_cvt_pk_fp8_f32(c, d, v, true);
    return (uint)v;
}
__device__ __forceinline__ unsigned char f2fp8(float x) {
    return (unsigned char)__builtin_amdgcn_cvt_pk_fp8_f32(x, 0.f, 0, false);
}

// async global->LDS, 16 bytes per lane; lds dest = wave-uniform base + lane*16
__device__ __forceinline__ void gload16(const void* g, void* l) {
    __builtin_amdgcn_global_load_lds(
        (const __attribute__((address_space(1))) unsigned int*)g,
        (__attribute__((address_space(3))) unsigned int*)l,
        16, 0, 0);
}

// ---------------- weight prep: fp32 -> bf16, fold softmax scale into Wq/bq ---
__global__ __launch_bounds__(256) void prep_weights(
    const float* __restrict__ wq, const float* __restrict__ bq,
    const float* __restrict__ wk, const float* __restrict__ bk,
    const float* __restrict__ wv, const float* __restrict__ wo,
    ushort* __restrict__ Wqk, ushort* __restrict__ Wv, ushort* __restrict__ Wo,
    float* __restrict__ bqk, float scale)
{
    int idx = blockIdx.x * 256 + threadIdx.x;
    if (idx < 1024 * 512) {
        float v = (idx < 262144) ? wq[idx] * scale : wk[idx - 262144];
        Wqk[idx] = f2bf(v);
    }
    if (idx < 262144) {
        Wv[idx] = f2bf(wv[idx]);
        Wo[idx] = f2bf(wo[idx]);
    }
    if (idx < 1024) bqk[idx] = (idx < 512) ? bq[idx] * scale : bk[idx - 512];
}

// ------- GroupNorm: [4,512,4096] fp32 -> bf16 TRANSPOSED hn_t[b][hw][c] -----
__global__ __launch_bounds__(256) void gn_kernel(
    const float* __restrict__ x, const float* __restrict__ gamma,
    const float* __restrict__ beta, ushort* __restrict__ hnt)
{
    int blk = blockIdx.x;          // b*32 + g, 128 total
    int b = blk >> 5, g = blk & 31;
    const float* xp = x + (size_t)blk * 65536;   // group chunk: 16 ch * 4096
    int tid = threadIdx.x;

    float s = 0.f, sq = 0.f;
    for (int i = tid * 4; i < 65536; i += 1024) {
        float4 v = *(const float4*)&xp[i];
        s  += v.x + v.y + v.z + v.w;
        sq += v.x * v.x + v.y * v.y + v.z * v.z + v.w * v.w;
    }
    #pragma unroll
    for (int off = 32; off; off >>= 1) {
        s  += __shfl_xor(s,  off, 64);
        sq += __shfl_xor(sq, off, 64);
    }
    __shared__ float red[8];
    if ((tid & 63) == 0) { red[(tid >> 6) * 2] = s; red[(tid >> 6) * 2 + 1] = sq; }
    __syncthreads();
    float ts = red[0] + red[2] + red[4] + red[6];
    float tq = red[1] + red[3] + red[5] + red[7];
    float mean = ts * (1.f / 65536.f);
    float var  = tq * (1.f / 65536.f) - mean * mean;
    float rstd = rsqrtf(var + 1e-6f);

    float a[16], c[16];
    #pragma unroll
    for (int ch = 0; ch < 16; ++ch) {
        float ga = gamma[g * 16 + ch], be = beta[g * 16 + ch];
        a[ch] = rstd * ga; c[ch] = be - mean * a[ch];
    }

    __shared__ ushort ls[16][256];
    for (int tile = 0; tile < 16; ++tile) {
        int i0 = tile * 256;
        __syncthreads();
        #pragma unroll
        for (int ch = 0; ch < 16; ++ch)
            ls[ch][tid] = f2bf(xp[ch * 4096 + i0 + tid] * a[ch] + c[ch]);
        __syncthreads();
        ushort t[16];
        #pragma unroll
        for (int ch = 0; ch < 16; ++ch) t[ch] = ls[ch][tid];
        size_t dst = ((size_t)b * 4096 + i0 + tid) * 512 + g * 16;
        *(uint4*)&hnt[dst]     = *(const uint4*)&t[0];
        *(uint4*)&hnt[dst + 8] = *(const uint4*)&t[8];
    }
}

// ---- softmax: bf16 S in -> fp8 (x256) P8 out, K-INTERLEAVED layout ---------
// Within each 64-byte j-group, 8-byte pieces are stored in the order
// [j0-7 | j32-39 | j8-15 | j40-47 | j16-23 | j48-55 | j24-31 | j56-63]
// so the PV kernel can fragment-read with a single conflict-clean b128.
__global__ __launch_bounds__(256) void softmax_kernel(
    const ushort* __restrict__ S, unsigned char* __restrict__ P8)
{
    size_t row = blockIdx.x;
    const ushort* p = S + row * 4096;
    int tid = threadIdx.x;

    ushort tmp[16];
    *(uint4*)&tmp[0] = *(const uint4*)&p[tid * 16];
    *(uint4*)&tmp[8] = *(const uint4*)&p[tid * 16 + 8];
    float v[16];
    float mx = -1e30f;
    #pragma unroll
    for (int j = 0; j < 16; ++j) { v[j] = bf2f(tmp[j]); mx = fmaxf(mx, v[j]); }
    #pragma unroll
    for (int off = 32; off; off >>= 1) mx = fmaxf(mx, __shfl_xor(mx, off, 64));
    __shared__ float ls[8];
    if ((tid & 63) == 0) ls[tid >> 6] = mx;
    __syncthreads();
    float m4 = fmaxf(fmaxf(ls[0], ls[1]), fmaxf(ls[2], ls[3]));
    float sum = 0.f;
    #pragma unroll
    for (int j = 0; j < 16; ++j) { v[j] = __expf(v[j] - m4); sum += v[j]; }
    #pragma unroll
    for (int off = 32; off; off >>= 1) sum += __shfl_xor(sum, off, 64);
    if ((tid & 63) == 0) ls[4 + (tid >> 6)] = sum;
    __syncthreads();
    // scale by 256 so diffuse probs (~2.4e-4) clear e4m3's subnormal floor
    float inv = 256.0f / (ls[4] + ls[5] + ls[6] + ls[7]);
    // thread handles js [tid*16, tid*16+16): pieces a0=(tid&3)*2, a0+1
    int u = tid & 3;
    size_t base = row * 4096 + (size_t)(tid >> 2) * 64
                + (u & 1) * 32 + (u >> 1) * 8;
    uint2 o0, o1;
    o0.x = pk4_fp8(v[0] * inv,  v[1] * inv,  v[2] * inv,  v[3] * inv);
    o0.y = pk4_fp8(v[4] * inv,  v[5] * inv,  v[6] * inv,  v[7] * inv);
    o1.x = pk4_fp8(v[8] * inv,  v[9] * inv,  v[10] * inv, v[11] * inv);
    o1.y = pk4_fp8(v[12] * inv, v[13] * inv, v[14] * inv, v[15] * inv);
    *(uint2*)&P8[base]      = o0;
    *(uint2*)&P8[base + 16] = o1;
}

// ---- NT bf16 MFMA GEMM, 128x128 tile, BK=64 (two 32-k sub-tiles/barrier) ---
// C[m,n] = sum_k A[m,k]*B[n,k]   A: [M][K] lda, B: [N][K] ldb (both K-contig)
// OUT: 0 bf16, 1 fp32 + resid, 2 fp8-e4m3 K-interleaved (see softmax note).
// BIAS: 0 none, 1 row, 2 col.
template <int BIAS, int OUT>
__global__ __launch_bounds__(256, 4) void gemm_nt(
    const ushort* __restrict__ Ag, const ushort* __restrict__ Bg,
    void* __restrict__ Cv,
    const float* __restrict__ bias, const float* __restrict__ resid,
    int N, int K, int lda, int ldb,
    long sA, long sB, long sC)
{
    const int bz = blockIdx.z;
    Ag += (size_t)bz * sA;
    Bg += (size_t)bz * sB;

    const int tid  = threadIdx.x;
    const int wave = tid >> 6, lane = tid & 63;
    const int q = lane >> 4, lr = lane & 15;
    const int m0 = blockIdx.x * 128, n0 = blockIdx.y * 128;   // m on X!
    const int wm = (wave >> 1) * 64, wn = (wave & 1) * 64;

    __shared__ __align__(16) ushort As[2][128 * 32];   // 2 x 8 KB
    __shared__ __align__(16) ushort Bs[2][128 * 32];   // 2 x 8 KB

    const int srow = wave * 32 + (lane >> 2);
    const int skc  = (lane & 3) << 3;
    const size_t aoff0 = (size_t)(m0 + srow) * lda + skc;
    const size_t aoff1 = aoff0 + (size_t)16 * lda;
    const size_t boff0 = (size_t)(n0 + srow) * ldb + skc;
    const size_t boff1 = boff0 + (size_t)16 * ldb;
    const int l0 = wave * 1024, l1 = wave * 1024 + 512;   // wave-uniform bases

    f32x4 acc[4][4] = {};

    for (int kb = 0; kb < K; kb += 64) {
        __syncthreads();
        gload16(&Ag[aoff0 + kb],      &As[0][l0]);
        gload16(&Ag[aoff1 + kb],      &As[0][l1]);
        gload16(&Ag[aoff0 + kb + 32], &As[1][l0]);
        gload16(&Ag[aoff1 + kb + 32], &As[1][l1]);
        gload16(&Bg[boff0 + kb],      &Bs[0][l0]);
        gload16(&Bg[boff1 + kb],      &Bs[0][l1]);
        gload16(&Bg[boff0 + kb + 32], &Bs[1][l0]);
        gload16(&Bg[boff1 + kb + 32], &Bs[1][l1]);
        __syncthreads();

        #pragma unroll
        for (int kh = 0; kh < 2; ++kh) {
            short8 af[4], bfr[4];
            #pragma unroll
            for (int mt = 0; mt < 4; ++mt)
                af[mt] = *(const short8*)&As[kh][(wm + mt * 16 + lr) * 32 + q * 8];
            #pragma unroll
            for (int nt = 0; nt < 4; ++nt)
                bfr[nt] = *(const short8*)&Bs[kh][(wn + nt * 16 + lr) * 32 + q * 8];
            #pragma unroll
            for (int mt = 0; mt < 4; ++mt)
                #pragma unroll
                for (int nt = 0; nt < 4; ++nt)
                    acc[mt][nt] = __builtin_amdgcn_mfma_f32_16x16x32_bf16(
                        af[mt], bfr[nt], acc[mt][nt], 0, 0, 0);
        }
    }

    #pragma unroll
    for (int mt = 0; mt < 4; ++mt) {
        int rb = m0 + wm + mt * 16 + q * 4;
        #pragma unroll
        for (int nt = 0; nt < 4; ++nt) {
            int cn = n0 + wn + nt * 16 + lr;
            #pragma unroll
            for (int t = 0; t < 4; ++t) {
                int r = rb + t;
                float v = acc[mt][nt][t];
                if (BIAS == 1) v += bias[r];
                if (BIAS == 2) v += bias[cn];
                if (OUT == 1) {
                    size_t o = (size_t)bz * sC + (size_t)r * N + cn;
                    ((float*)Cv)[o] = v + resid[o];
                } else if (OUT == 2) {
                    // K-interleave the column index within its 64-group
                    int w = cn & 63, a = w >> 3;
                    int sp = (cn & ~63) | ((a & 3) * 16 + (a >> 2) * 8 + (w & 7));
                    ((unsigned char*)Cv)[(size_t)bz * sC + (size_t)r * N + sp] =
                        f2fp8(v);
                } else {
                    size_t o = (size_t)bz * sC + (size_t)r * N + cn;
                    ((ushort*)Cv)[o] = f2bf(v);
                }
            }
        }
    }
}

// ---- PV GEMM, fp8 e4m3, 128x128 tile, BK=128 fp8 elems per barrier ---------
// Ot[i][c] = (1/256) * sum_j P8[i,j] * V8[c,j].  M=4096, N=512, K=4096.
// P8/V8 are K-interleaved in global (see softmax), so each fragment pair
// (kk=0, kk=1) is one conflict-clean ds_read_b128 at row*64 + q*16.
__global__ __launch_bounds__(256, 4) void gemm_pv(
    const unsigned char* __restrict__ P8, const unsigned char* __restrict__ V8,
    ushort* __restrict__ Ot)
{
    const int bz = blockIdx.z;
    const unsigned char* Ag = P8 + (size_t)bz * 16777216;   // 4096*4096
    const unsigned char* Bg = V8 + (size_t)bz * 2097152;    // 512*4096

    const int tid  = threadIdx.x;
    const int wave = tid >> 6, lane = tid & 63;
    const int q = lane >> 4, lr = lane & 15;
    const int m0 = blockIdx.x * 128, n0 = blockIdx.y * 128;  // m on X (XCD share)
    const int wm = (wave >> 1) * 64, wn = (wave & 1) * 64;

    __shared__ __align__(16) unsigned char As[2][128 * 64];  // 2 x 8 KB
    __shared__ __align__(16) unsigned char Bs[2][128 * 64];  // 2 x 8 KB

    const int srow = wave * 32 + (lane >> 2);
    const int soff = (lane & 3) << 4;               // 16-B chunk in 64-B row
    const size_t a0 = (size_t)(m0 + srow) * 4096 + soff;
    const size_t a1 = a0 + (size_t)16 * 4096;
    const size_t b0 = (size_t)(n0 + srow) * 4096 + soff;
    const size_t b1 = b0 + (size_t)16 * 4096;
    const int l0 = wave * 2048, l1 = wave * 2048 + 1024;

    f32x4 acc[4][4] = {};

    for (int kb = 0; kb < 4096; kb += 128) {
        __syncthreads();
        gload16(Ag + a0 + kb,      &As[0][l0]);
        gload16(Ag + a1 + kb,      &As[0][l1]);
        gload16(Ag + a0 + kb + 64, &As[1][l0]);
        gload16(Ag + a1 + kb + 64, &As[1][l1]);
        gload16(Bg + b0 + kb,      &Bs[0][l0]);
        gload16(Bg + b1 + kb,      &Bs[0][l1]);
        gload16(Bg + b0 + kb + 64, &Bs[1][l0]);
        gload16(Bg + b1 + kb + 64, &Bs[1][l1]);
        __syncthreads();

        #pragma unroll
        for (int kh = 0; kh < 2; ++kh) {
            llong2 af[4], bf[4];
            #pragma unroll
            for (int mt = 0; mt < 4; ++mt)
                af[mt] = *(const llong2*)
                    &As[kh][(wm + mt * 16 + lr) * 64 + q * 16];
            #pragma unroll
            for (int nt = 0; nt < 4; ++nt)
                bf[nt] = *(const llong2*)
                    &Bs[kh][(wn + nt * 16 + lr) * 64 + q * 16];
            #pragma unroll
            for (int mt = 0; mt < 4; ++mt)
                #pragma unroll
                for (int nt = 0; nt < 4; ++nt)
                    acc[mt][nt] = __builtin_amdgcn_mfma_f32_16x16x32_fp8_fp8(
                        af[mt].x, bf[nt].x, acc[mt][nt], 0, 0, 0);
            #pragma unroll
            for (int mt = 0; mt < 4; ++mt)
                #pragma unroll
                for (int nt = 0; nt < 4; ++nt)
                    acc[mt][nt] = __builtin_amdgcn_mfma_f32_16x16x32_fp8_fp8(
                        af[mt].y, bf[nt].y, acc[mt][nt], 0, 0, 0);
        }
    }

    #pragma unroll
    for (int mt = 0; mt < 4; ++mt) {
        int rb = m0 + wm + mt * 16 + q * 4;
        #pragma unroll
        for (int nt = 0; nt < 4; ++nt) {
            int cn = n0 + wn + nt * 16 + lr;
            #pragma unroll
            for (int t = 0; t < 4; ++t) {
                size_t o = (size_t)bz * 2097152 + (size_t)(rb + t) * 512 + cn;
                Ot[o] = f2bf(acc[mt][nt][t] * (1.f / 256.f));
            }
        }
    }
}

// ---------------- launch -----------------------------------------------------
extern "C" void kernel_launch(void* const* d_in, const int* in_sizes, int n_in,
                              void* d_out, int out_size, void* d_ws, size_t ws_size,
                              hipStream_t stream)
{
    const float* x   = (const float*)d_in[0];
    const float* gnw = (const float*)d_in[1];
    const float* gnb = (const float*)d_in[2];
    const float* wq  = (const float*)d_in[3];
    const float* bq  = (const float*)d_in[4];
    const float* wk  = (const float*)d_in[5];
    const float* bk  = (const float*)d_in[6];
    const float* wv  = (const float*)d_in[7];
    const float* bv  = (const float*)d_in[8];
    const float* wo  = (const float*)d_in[9];
    const float* bo  = (const float*)d_in[10];
    float* out = (float*)d_out;

    char* ws = (char*)d_ws;
    // ws layout with lifetime overlays (footprint ~212 MB):
    //  [0,128M)      S (bf16 scores)  -> dead after softmax; Ot overlays [0,16M)
    //  [128M,144M)   hnt              -> dead after scores
    //  [144M,176M)   QKt              -> dead after scores
    //  [128M,192M)   P8 (fp8 x256)    -> overlays hnt+QKt, written by softmax
    //  [192M,200M)   V8 (fp8)
    //  [200M+..]     weights
    ushort*        S   = (ushort*)(ws);
    ushort*        Ot  = (ushort*)(ws);                       // overlay of S
    ushort*        hnt = (ushort*)(ws + 134217728);
    ushort*        QKt = (ushort*)(ws + 150994944);
    unsigned char* P8  = (unsigned char*)(ws + 134217728);    // overlay
    unsigned char* V8  = (unsigned char*)(ws + 201326592);
    ushort*        Wqk = (ushort*)(ws + 209715200);
    ushort*        Wv  = (ushort*)(ws + 210763776);
    ushort*        Wo  = (ushort*)(ws + 211288064);
    float*         bqk = (float*) (ws + 211812352);

    const float scale = 1.0f / sqrtf(512.0f);
    const long sHW  = 512L * 4096;     // 2 M elems
    const long sQK  = 4096L * 1024;
    const long sP   = 4096L * 4096;

    prep_weights<<<2048, 256, 0, stream>>>(wq, bq, wk, bk, wv, wo,
                                           Wqk, Wv, Wo, bqk, scale);
    gn_kernel<<<128, 256, 0, stream>>>(x, gnw, gnb, hnt);

    // QKt[i][o] = hn_t[i][c] . Wqk[o][c]  (M=4096, N=1024, K=512), col-bias
    gemm_nt<2, 0><<<dim3(32, 8, 4), 256, 0, stream>>>(
        hnt, Wqk, QKt, bqk, nullptr,
        1024, 512, 512, 512, sHW, 0L, sQK);

    // V8[o][j] = fp8( Wv[o][c] . hn_t[j][c] + bv ), K-interleaved
    gemm_nt<1, 2><<<dim3(4, 32, 4), 256, 0, stream>>>(
        Wv, hnt, V8, bv, nullptr,
        4096, 512, 512, 512, 0L, sHW, sHW);

    // S[i][j] = Qt[i][c] . Kt[j][c]  (M=N=4096, K=512)
    gemm_nt<0, 0><<<dim3(32, 32, 4), 256, 0, stream>>>(
        QKt, QKt + 512, S, nullptr, nullptr,
        4096, 512, 1024, 1024, sQK, sQK, sP);

    softmax_kernel<<<16384, 256, 0, stream>>>(S, P8);

    // Ot[i][c] = (1/256) P8[i][j] . V8[c][j]  (fp8 MFMA, BK=128)
    gemm_pv<<<dim3(32, 4, 4), 256, 0, stream>>>(P8, V8, Ot);

    // out[o][i] = x + Wo[o][c] . Ot[i][c] + bo  (M=512, N=4096, K=512), fp32
    gemm_nt<1, 1><<<dim3(4, 32, 4), 256, 0, stream>>>(
        Wo, Ot, out, bo, x,
        4096, 512, 512, 512, 0L, sHW, sHW);
}

// Round 9
// 345.801 us; speedup vs baseline: 1.2867x; 1.0624x over previous
//
#include <hip/hip_runtime.h>
#include <math.h>

using short8 = __attribute__((ext_vector_type(8))) short;
using f32x4  = __attribute__((ext_vector_type(4))) float;
using llong2 = __attribute__((ext_vector_type(2))) long long;
using i32x8  = __attribute__((ext_vector_type(8))) int;

__device__ __forceinline__ ushort f2bf(float f) {
    union { float f; uint u; } c; c.f = f;
    uint u = c.u;
    uint r = (u + 0x7FFFu + ((u >> 16) & 1u)) >> 16;
    return (ushort)r;
}
__device__ __forceinline__ float bf2f(ushort h) {
    union { uint u; float f; } c; c.u = ((uint)h) << 16;
    return c.f;
}
// pack 4 floats -> 4 fp8 e4m3 (OCP on gfx950) in one dword
__device__ __forceinline__ uint pk4_fp8(float a, float b, float c, float d) {
    int v = __builtin_amdgcn_cvt_pk_fp8_f32(a, b, 0, false);
    v = __builtin_amdgcn_cvt_pk_fp8_f32(c, d, v, true);
    return (uint)v;
}
__device__ __forceinline__ unsigned char f2fp8(float x) {
    return (unsigned char)__builtin_amdgcn_cvt_pk_fp8_f32(x, 0.f, 0, false);
}

// async global->LDS, 16 bytes per lane; lds dest = wave-uniform base + lane*16
__device__ __forceinline__ void gload16(const void* g, void* l) {
    __builtin_amdgcn_global_load_lds(
        (const __attribute__((address_space(1))) unsigned int*)g,
        (__attribute__((address_space(3))) unsigned int*)l,
        16, 0, 0);
}

// ---------------- weight prep: fp32 -> bf16, fold softmax scale into Wq/bq ---
__global__ __launch_bounds__(256) void prep_weights(
    const float* __restrict__ wq, const float* __restrict__ bq,
    const float* __restrict__ wk, const float* __restrict__ bk,
    const float* __restrict__ wv, const float* __restrict__ wo,
    ushort* __restrict__ Wqk, ushort* __restrict__ Wv, ushort* __restrict__ Wo,
    float* __restrict__ bqk, float scale)
{
    int idx = blockIdx.x * 256 + threadIdx.x;
    if (idx < 1024 * 512) {
        float v = (idx < 262144) ? wq[idx] * scale : wk[idx - 262144];
        Wqk[idx] = f2bf(v);
    }
    if (idx < 262144) {
        Wv[idx] = f2bf(wv[idx]);
        Wo[idx] = f2bf(wo[idx]);
    }
    if (idx < 1024) bqk[idx] = (idx < 512) ? bq[idx] * scale : bk[idx - 512];
}

// ------- GroupNorm: [4,512,4096] fp32 -> bf16 TRANSPOSED hn_t[b][hw][c] -----
__global__ __launch_bounds__(256) void gn_kernel(
    const float* __restrict__ x, const float* __restrict__ gamma,
    const float* __restrict__ beta, ushort* __restrict__ hnt)
{
    int blk = blockIdx.x;          // b*32 + g, 128 total
    int b = blk >> 5, g = blk & 31;
    const float* xp = x + (size_t)blk * 65536;   // group chunk: 16 ch * 4096
    int tid = threadIdx.x;

    float s = 0.f, sq = 0.f;
    for (int i = tid * 4; i < 65536; i += 1024) {
        float4 v = *(const float4*)&xp[i];
        s  += v.x + v.y + v.z + v.w;
        sq += v.x * v.x + v.y * v.y + v.z * v.z + v.w * v.w;
    }
    #pragma unroll
    for (int off = 32; off; off >>= 1) {
        s  += __shfl_xor(s,  off, 64);
        sq += __shfl_xor(sq, off, 64);
    }
    __shared__ float red[8];
    if ((tid & 63) == 0) { red[(tid >> 6) * 2] = s; red[(tid >> 6) * 2 + 1] = sq; }
    __syncthreads();
    float ts = red[0] + red[2] + red[4] + red[6];
    float tq = red[1] + red[3] + red[5] + red[7];
    float mean = ts * (1.f / 65536.f);
    float var  = tq * (1.f / 65536.f) - mean * mean;
    float rstd = rsqrtf(var + 1e-6f);

    float a[16], c[16];
    #pragma unroll
    for (int ch = 0; ch < 16; ++ch) {
        float ga = gamma[g * 16 + ch], be = beta[g * 16 + ch];
        a[ch] = rstd * ga; c[ch] = be - mean * a[ch];
    }

    __shared__ ushort ls[16][256];
    for (int tile = 0; tile < 16; ++tile) {
        int i0 = tile * 256;
        __syncthreads();
        #pragma unroll
        for (int ch = 0; ch < 16; ++ch)
            ls[ch][tid] = f2bf(xp[ch * 4096 + i0 + tid] * a[ch] + c[ch]);
        __syncthreads();
        ushort t[16];
        #pragma unroll
        for (int ch = 0; ch < 16; ++ch) t[ch] = ls[ch][tid];
        size_t dst = ((size_t)b * 4096 + i0 + tid) * 512 + g * 16;
        *(uint4*)&hnt[dst]     = *(const uint4*)&t[0];
        *(uint4*)&hnt[dst + 8] = *(const uint4*)&t[8];
    }
}

// ---- softmax: bf16 S in -> fp8 (x256) P8 out, K-INTERLEAVED layout ---------
// Within each 64-byte j-group, 8-byte pieces are stored in the order
// [j0-7 | j32-39 | j8-15 | j40-47 | j16-23 | j48-55 | j24-31 | j56-63]
// so the PV kernel can fragment-read with a single conflict-clean b128.
__global__ __launch_bounds__(256) void softmax_kernel(
    const ushort* __restrict__ S, unsigned char* __restrict__ P8)
{
    size_t row = blockIdx.x;
    const ushort* p = S + row * 4096;
    int tid = threadIdx.x;

    ushort tmp[16];
    *(uint4*)&tmp[0] = *(const uint4*)&p[tid * 16];
    *(uint4*)&tmp[8] = *(const uint4*)&p[tid * 16 + 8];
    float v[16];
    float mx = -1e30f;
    #pragma unroll
    for (int j = 0; j < 16; ++j) { v[j] = bf2f(tmp[j]); mx = fmaxf(mx, v[j]); }
    #pragma unroll
    for (int off = 32; off; off >>= 1) mx = fmaxf(mx, __shfl_xor(mx, off, 64));
    __shared__ float ls[8];
    if ((tid & 63) == 0) ls[tid >> 6] = mx;
    __syncthreads();
    float m4 = fmaxf(fmaxf(ls[0], ls[1]), fmaxf(ls[2], ls[3]));
    float sum = 0.f;
    #pragma unroll
    for (int j = 0; j < 16; ++j) { v[j] = __expf(v[j] - m4); sum += v[j]; }
    #pragma unroll
    for (int off = 32; off; off >>= 1) sum += __shfl_xor(sum, off, 64);
    if ((tid & 63) == 0) ls[4 + (tid >> 6)] = sum;
    __syncthreads();
    // scale by 256 so diffuse probs (~2.4e-4) clear e4m3's subnormal floor
    float inv = 256.0f / (ls[4] + ls[5] + ls[6] + ls[7]);
    int u = tid & 3;
    size_t base = row * 4096 + (size_t)(tid >> 2) * 64
                + (u & 1) * 32 + (u >> 1) * 8;
    uint2 o0, o1;
    o0.x = pk4_fp8(v[0] * inv,  v[1] * inv,  v[2] * inv,  v[3] * inv);
    o0.y = pk4_fp8(v[4] * inv,  v[5] * inv,  v[6] * inv,  v[7] * inv);
    o1.x = pk4_fp8(v[8] * inv,  v[9] * inv,  v[10] * inv, v[11] * inv);
    o1.y = pk4_fp8(v[12] * inv, v[13] * inv, v[14] * inv, v[15] * inv);
    *(uint2*)&P8[base]      = o0;
    *(uint2*)&P8[base + 16] = o1;
}

// ---- NT bf16 MFMA GEMM, 128x128 tile, BK=64 (two 32-k sub-tiles/barrier) ---
// C[m,n] = sum_k A[m,k]*B[n,k]   A: [M][K] lda, B: [N][K] ldb (both K-contig)
// OUT: 0 bf16, 1 fp32 + resid, 2 fp8 K-interleaved, 3 split Q/K fp8 (Q x16).
// BIAS: 0 none, 1 row, 2 col.
template <int BIAS, int OUT>
__global__ __launch_bounds__(256, 4) void gemm_nt(
    const ushort* __restrict__ Ag, const ushort* __restrict__ Bg,
    void* __restrict__ Cv, void* __restrict__ Cv2,
    const float* __restrict__ bias, const float* __restrict__ resid,
    int N, int K, int lda, int ldb,
    long sA, long sB, long sC)
{
    const int bz = blockIdx.z;
    Ag += (size_t)bz * sA;
    Bg += (size_t)bz * sB;

    const int tid  = threadIdx.x;
    const int wave = tid >> 6, lane = tid & 63;
    const int q = lane >> 4, lr = lane & 15;
    const int m0 = blockIdx.x * 128, n0 = blockIdx.y * 128;   // m on X!
    const int wm = (wave >> 1) * 64, wn = (wave & 1) * 64;

    __shared__ __align__(16) ushort As[2][128 * 32];   // 2 x 8 KB
    __shared__ __align__(16) ushort Bs[2][128 * 32];   // 2 x 8 KB

    const int srow = wave * 32 + (lane >> 2);
    const int skc  = (lane & 3) << 3;
    const size_t aoff0 = (size_t)(m0 + srow) * lda + skc;
    const size_t aoff1 = aoff0 + (size_t)16 * lda;
    const size_t boff0 = (size_t)(n0 + srow) * ldb + skc;
    const size_t boff1 = boff0 + (size_t)16 * ldb;
    const int l0 = wave * 1024, l1 = wave * 1024 + 512;   // wave-uniform bases

    f32x4 acc[4][4] = {};

    for (int kb = 0; kb < K; kb += 64) {
        __syncthreads();
        gload16(&Ag[aoff0 + kb],      &As[0][l0]);
        gload16(&Ag[aoff1 + kb],      &As[0][l1]);
        gload16(&Ag[aoff0 + kb + 32], &As[1][l0]);
        gload16(&Ag[aoff1 + kb + 32], &As[1][l1]);
        gload16(&Bg[boff0 + kb],      &Bs[0][l0]);
        gload16(&Bg[boff1 + kb],      &Bs[0][l1]);
        gload16(&Bg[boff0 + kb + 32], &Bs[1][l0]);
        gload16(&Bg[boff1 + kb + 32], &Bs[1][l1]);
        __syncthreads();

        #pragma unroll
        for (int kh = 0; kh < 2; ++kh) {
            short8 af[4], bfr[4];
            #pragma unroll
            for (int mt = 0; mt < 4; ++mt)
                af[mt] = *(const short8*)&As[kh][(wm + mt * 16 + lr) * 32 + q * 8];
            #pragma unroll
            for (int nt = 0; nt < 4; ++nt)
                bfr[nt] = *(const short8*)&Bs[kh][(wn + nt * 16 + lr) * 32 + q * 8];
            #pragma unroll
            for (int mt = 0; mt < 4; ++mt)
                #pragma unroll
                for (int nt = 0; nt < 4; ++nt)
                    acc[mt][nt] = __builtin_amdgcn_mfma_f32_16x16x32_bf16(
                        af[mt], bfr[nt], acc[mt][nt], 0, 0, 0);
        }
    }

    #pragma unroll
    for (int mt = 0; mt < 4; ++mt) {
        int rb = m0 + wm + mt * 16 + q * 4;
        #pragma unroll
        for (int nt = 0; nt < 4; ++nt) {
            int cn = n0 + wn + nt * 16 + lr;
            #pragma unroll
            for (int t = 0; t < 4; ++t) {
                int r = rb + t;
                float v = acc[mt][nt][t];
                if (BIAS == 1) v += bias[r];
                if (BIAS == 2) v += bias[cn];
                if (OUT == 1) {
                    size_t o = (size_t)bz * sC + (size_t)r * N + cn;
                    ((float*)Cv)[o] = v + resid[o];
                } else if (OUT == 2) {
                    // K-interleave the column index within its 64-group
                    int w = cn & 63, a = w >> 3;
                    int sp = (cn & ~63) | ((a & 3) * 16 + (a >> 2) * 8 + (w & 7));
                    ((unsigned char*)Cv)[(size_t)bz * sC + (size_t)r * N + sp] =
                        f2fp8(v);
                } else if (OUT == 3) {
                    // split 1024-wide output: cols [0,512) -> Q8 (x16),
                    // cols [512,1024) -> K8. sC = per-batch elems of each.
                    if (cn < 512)
                        ((unsigned char*)Cv)[(size_t)bz * sC + (size_t)r * 512 + cn]
                            = f2fp8(v * 16.f);
                    else
                        ((unsigned char*)Cv2)[(size_t)bz * sC + (size_t)r * 512 + (cn - 512)]
                            = f2fp8(v);
                } else {
                    size_t o = (size_t)bz * sC + (size_t)r * N + cn;
                    ((ushort*)Cv)[o] = f2bf(v);
                }
            }
        }
    }
}

// ---- scores GEMM, MX-fp8 (K=128 scaled MFMA), 128x128 tile -----------------
// S[i][j] = sum_c Q8[i,c]*2^-4 * K8[j,c].  M=N=4096, K=512 bytes, 4 K-iters.
// LDS rows are 128 B with XOR-swizzled 16B pieces: slot p of row r holds
// global piece p^(r&7), realized by permuting each lane's GLOBAL source
// (dest stays wave-uniform + lane*16). Fragment reads then hit all 32 banks
// at 2 lanes/bank (free).
__global__ __launch_bounds__(256, 2) void gemm_qk(
    const unsigned char* __restrict__ Q8, const unsigned char* __restrict__ K8,
    ushort* __restrict__ S)
{
    const int bz = blockIdx.z;
    const unsigned char* Ag = Q8 + (size_t)bz * 2097152;   // 4096*512
    const unsigned char* Bg = K8 + (size_t)bz * 2097152;

    const int tid  = threadIdx.x;
    const int wave = tid >> 6, lane = tid & 63;
    const int q = lane >> 4, lr = lane & 15;
    const int m0 = blockIdx.x * 128, n0 = blockIdx.y * 128;
    const int wm = (wave >> 1) * 64, wn = (wave & 1) * 64;

    __shared__ __align__(16) unsigned char As[128 * 128];   // 16 KB
    __shared__ __align__(16) unsigned char Bs[128 * 128];   // 16 KB

    // staging: lane i covers local row i>>3, swizzled piece (i&7)^((i>>3)&7)
    const int lrow = lane >> 3;
    const size_t laneoff = (size_t)lrow * 512 + ((lane & 7) ^ (lrow & 7)) * 16;
    const size_t abase = (size_t)(m0 + wave * 32) * 512 + laneoff;
    const size_t bbase = (size_t)(n0 + wave * 32) * 512 + laneoff;
    unsigned char* lA = &As[wave * 32 * 128];   // wave-uniform
    unsigned char* lB = &Bs[wave * 32 * 128];

    // fragment read swizzle: row&7 == lr&7 for all tiles (offsets mult of 8)
    const int e0 = (2 * q) ^ (lr & 7), e1 = e0 ^ 1;

    f32x4 acc[4][4] = {};
    const int sA = 0x7B7B7B7B;   // e8m0 2^-4 (undo the x16 in Q8)
    const int sB = 0x7F7F7F7F;   // e8m0 1.0

    for (int kb = 0; kb < 512; kb += 128) {
        __syncthreads();
        #pragma unroll
        for (int t = 0; t < 4; ++t) {
            gload16(Ag + abase + (size_t)t * 4096 + kb, lA + t * 1024);
            gload16(Bg + bbase + (size_t)t * 4096 + kb, lB + t * 1024);
        }
        __syncthreads();

        i32x8 af[4], bf[4];
        #pragma unroll
        for (int mt = 0; mt < 4; ++mt) {
            int r = wm + mt * 16 + lr;
            union { uint4 v[2]; i32x8 f; } u;
            u.v[0] = *(const uint4*)&As[r * 128 + e0 * 16];
            u.v[1] = *(const uint4*)&As[r * 128 + e1 * 16];
            af[mt] = u.f;
        }
        #pragma unroll
        for (int nt = 0; nt < 4; ++nt) {
            int r = wn + nt * 16 + lr;
            union { uint4 v[2]; i32x8 f; } u;
            u.v[0] = *(const uint4*)&Bs[r * 128 + e0 * 16];
            u.v[1] = *(const uint4*)&Bs[r * 128 + e1 * 16];
            bf[nt] = u.f;
        }
        #pragma unroll
        for (int mt = 0; mt < 4; ++mt)
            #pragma unroll
            for (int nt = 0; nt < 4; ++nt)
                acc[mt][nt] = __builtin_amdgcn_mfma_scale_f32_16x16x128_f8f6f4(
                    af[mt], bf[nt], acc[mt][nt], 0, 0, 0, sA, 0, sB);
    }

    #pragma unroll
    for (int mt = 0; mt < 4; ++mt) {
        int rb = m0 + wm + mt * 16 + q * 4;
        #pragma unroll
        for (int nt = 0; nt < 4; ++nt) {
            int cn = n0 + wn + nt * 16 + lr;
            #pragma unroll
            for (int t = 0; t < 4; ++t) {
                size_t o = (size_t)bz * 16777216 + (size_t)(rb + t) * 4096 + cn;
                S[o] = f2bf(acc[mt][nt][t]);
            }
        }
    }
}

// ---- PV GEMM, fp8 e4m3, 128x128 tile, BK=128 fp8 elems per barrier ---------
__global__ __launch_bounds__(256, 4) void gemm_pv(
    const unsigned char* __restrict__ P8, const unsigned char* __restrict__ V8,
    ushort* __restrict__ Ot)
{
    const int bz = blockIdx.z;
    const unsigned char* Ag = P8 + (size_t)bz * 16777216;   // 4096*4096
    const unsigned char* Bg = V8 + (size_t)bz * 2097152;    // 512*4096

    const int tid  = threadIdx.x;
    const int wave = tid >> 6, lane = tid & 63;
    const int q = lane >> 4, lr = lane & 15;
    const int m0 = blockIdx.x * 128, n0 = blockIdx.y * 128;  // m on X (XCD share)
    const int wm = (wave >> 1) * 64, wn = (wave & 1) * 64;

    __shared__ __align__(16) unsigned char As[2][128 * 64];  // 2 x 8 KB
    __shared__ __align__(16) unsigned char Bs[2][128 * 64];  // 2 x 8 KB

    const int srow = wave * 32 + (lane >> 2);
    const int soff = (lane & 3) << 4;               // 16-B chunk in 64-B row
    const size_t a0 = (size_t)(m0 + srow) * 4096 + soff;
    const size_t a1 = a0 + (size_t)16 * 4096;
    const size_t b0 = (size_t)(n0 + srow) * 4096 + soff;
    const size_t b1 = b0 + (size_t)16 * 4096;
    const int l0 = wave * 2048, l1 = wave * 2048 + 1024;

    f32x4 acc[4][4] = {};

    for (int kb = 0; kb < 4096; kb += 128) {
        __syncthreads();
        gload16(Ag + a0 + kb,      &As[0][l0]);
        gload16(Ag + a1 + kb,      &As[0][l1]);
        gload16(Ag + a0 + kb + 64, &As[1][l0]);
        gload16(Ag + a1 + kb + 64, &As[1][l1]);
        gload16(Bg + b0 + kb,      &Bs[0][l0]);
        gload16(Bg + b1 + kb,      &Bs[0][l1]);
        gload16(Bg + b0 + kb + 64, &Bs[1][l0]);
        gload16(Bg + b1 + kb + 64, &Bs[1][l1]);
        __syncthreads();

        #pragma unroll
        for (int kh = 0; kh < 2; ++kh) {
            llong2 af[4], bf[4];
            #pragma unroll
            for (int mt = 0; mt < 4; ++mt)
                af[mt] = *(const llong2*)
                    &As[kh][(wm + mt * 16 + lr) * 64 + q * 16];
            #pragma unroll
            for (int nt = 0; nt < 4; ++nt)
                bf[nt] = *(const llong2*)
                    &Bs[kh][(wn + nt * 16 + lr) * 64 + q * 16];
            #pragma unroll
            for (int mt = 0; mt < 4; ++mt)
                #pragma unroll
                for (int nt = 0; nt < 4; ++nt)
                    acc[mt][nt] = __builtin_amdgcn_mfma_f32_16x16x32_fp8_fp8(
                        af[mt].x, bf[nt].x, acc[mt][nt], 0, 0, 0);
            #pragma unroll
            for (int mt = 0; mt < 4; ++mt)
                #pragma unroll
                for (int nt = 0; nt < 4; ++nt)
                    acc[mt][nt] = __builtin_amdgcn_mfma_f32_16x16x32_fp8_fp8(
                        af[mt].y, bf[nt].y, acc[mt][nt], 0, 0, 0);
        }
    }

    #pragma unroll
    for (int mt = 0; mt < 4; ++mt) {
        int rb = m0 + wm + mt * 16 + q * 4;
        #pragma unroll
        for (int nt = 0; nt < 4; ++nt) {
            int cn = n0 + wn + nt * 16 + lr;
            #pragma unroll
            for (int t = 0; t < 4; ++t) {
                size_t o = (size_t)bz * 2097152 + (size_t)(rb + t) * 512 + cn;
                Ot[o] = f2bf(acc[mt][nt][t] * (1.f / 256.f));
            }
        }
    }
}

// ---------------- launch -----------------------------------------------------
extern "C" void kernel_launch(void* const* d_in, const int* in_sizes, int n_in,
                              void* d_out, int out_size, void* d_ws, size_t ws_size,
                              hipStream_t stream)
{
    const float* x   = (const float*)d_in[0];
    const float* gnw = (const float*)d_in[1];
    const float* gnb = (const float*)d_in[2];
    const float* wq  = (const float*)d_in[3];
    const float* bq  = (const float*)d_in[4];
    const float* wk  = (const float*)d_in[5];
    const float* bk  = (const float*)d_in[6];
    const float* wv  = (const float*)d_in[7];
    const float* bv  = (const float*)d_in[8];
    const float* wo  = (const float*)d_in[9];
    const float* bo  = (const float*)d_in[10];
    float* out = (float*)d_out;

    char* ws = (char*)d_ws;
    // ws layout with lifetime overlays (~212 MB):
    //  [0,128M)      S (bf16 scores)  -> dead after softmax; Ot overlays [0,16M)
    //  [128M,144M)   hnt              -> dead after projections
    //  [144M,152M)   Q8, [152M,160M) K8 -> dead after scores
    //  [128M,192M)   P8 (fp8 x256)    -> overlay, written by softmax
    //  [192M,200M)   V8 (fp8)
    //  [200M+..]     weights
    ushort*        S   = (ushort*)(ws);
    ushort*        Ot  = (ushort*)(ws);                       // overlay of S
    ushort*        hnt = (ushort*)(ws + 134217728);
    unsigned char* Q8  = (unsigned char*)(ws + 150994944);
    unsigned char* K8  = (unsigned char*)(ws + 159383552);
    unsigned char* P8  = (unsigned char*)(ws + 134217728);    // overlay
    unsigned char* V8  = (unsigned char*)(ws + 201326592);
    ushort*        Wqk = (ushort*)(ws + 209715200);
    ushort*        Wv  = (ushort*)(ws + 210763776);
    ushort*        Wo  = (ushort*)(ws + 211288064);
    float*         bqk = (float*) (ws + 211812352);

    const float scale = 1.0f / sqrtf(512.0f);
    const long sHW  = 512L * 4096;     // 2 M elems

    prep_weights<<<2048, 256, 0, stream>>>(wq, bq, wk, bk, wv, wo,
                                           Wqk, Wv, Wo, bqk, scale);
    gn_kernel<<<128, 256, 0, stream>>>(x, gnw, gnb, hnt);

    // Q8[i][c]=fp8(16*q), K8[j][c]=fp8(k)  (M=4096, N=1024, K=512), col-bias
    gemm_nt<2, 3><<<dim3(32, 8, 4), 256, 0, stream>>>(
        hnt, Wqk, Q8, K8, bqk, nullptr,
        1024, 512, 512, 512, sHW, 0L, sHW);

    // V8[o][j] = fp8( Wv[o][c] . hn_t[j][c] + bv ), K-interleaved
    gemm_nt<1, 2><<<dim3(4, 32, 4), 256, 0, stream>>>(
        Wv, hnt, V8, nullptr, bv, nullptr,
        4096, 512, 512, 512, 0L, sHW, sHW);

    // S[i][j] = (Q8*2^-4).K8  (MX fp8 MFMA, K=128/inst, 4 K-iters)
    gemm_qk<<<dim3(32, 32, 4), 256, 0, stream>>>(Q8, K8, S);

    softmax_kernel<<<16384, 256, 0, stream>>>(S, P8);

    // Ot[i][c] = (1/256) P8[i][j] . V8[c][j]  (fp8 MFMA, BK=128)
    gemm_pv<<<dim3(32, 4, 4), 256, 0, stream>>>(P8, V8, Ot);

    // out[o][i] = x + Wo[o][c] . Ot[i][c] + bo  (M=512, N=4096, K=512), fp32
    gemm_nt<1, 1><<<dim3(4, 32, 4), 256, 0, stream>>>(
        Wo, Ot, out, nullptr, bo, x,
        4096, 512, 512, 512, 0L, sHW, sHW);
}

// Round 10
// 304.918 us; speedup vs baseline: 1.4592x; 1.1341x over previous
//
#include <hip/hip_runtime.h>
#include <math.h>

using short8 = __attribute__((ext_vector_type(8))) short;
using f32x4  = __attribute__((ext_vector_type(4))) float;
using llong2 = __attribute__((ext_vector_type(2))) long long;
using i32x8  = __attribute__((ext_vector_type(8))) int;

__device__ __forceinline__ ushort f2bf(float f) {
    union { float f; uint u; } c; c.f = f;
    uint u = c.u;
    uint r = (u + 0x7FFFu + ((u >> 16) & 1u)) >> 16;
    return (ushort)r;
}
__device__ __forceinline__ float bf2f(ushort h) {
    union { uint u; float f; } c; c.u = ((uint)h) << 16;
    return c.f;
}
// pack 4 floats -> 4 fp8 e4m3 (OCP on gfx950) in one dword
__device__ __forceinline__ uint pk4_fp8(float a, float b, float c, float d) {
    int v = __builtin_amdgcn_cvt_pk_fp8_f32(a, b, 0, false);
    v = __builtin_amdgcn_cvt_pk_fp8_f32(c, d, v, true);
    return (uint)v;
}
__device__ __forceinline__ unsigned char f2fp8(float x) {
    return (unsigned char)__builtin_amdgcn_cvt_pk_fp8_f32(x, 0.f, 0, false);
}

// async global->LDS, 16 bytes per lane; lds dest = wave-uniform base + lane*16
__device__ __forceinline__ void gload16(const void* g, void* l) {
    __builtin_amdgcn_global_load_lds(
        (const __attribute__((address_space(1))) unsigned int*)g,
        (__attribute__((address_space(3))) unsigned int*)l,
        16, 0, 0);
}

// ---- weight prep: fp32 -> bf16, fold softmax scale into Wq/bq; zero stats --
__global__ __launch_bounds__(256) void prep_weights(
    const float* __restrict__ wq, const float* __restrict__ bq,
    const float* __restrict__ wk, const float* __restrict__ bk,
    const float* __restrict__ wv, const float* __restrict__ wo,
    ushort* __restrict__ Wqk, ushort* __restrict__ Wv, ushort* __restrict__ Wo,
    float* __restrict__ bqk, float* __restrict__ stats, float scale)
{
    int idx = blockIdx.x * 256 + threadIdx.x;
    if (idx < 1024 * 512) {
        float v = (idx < 262144) ? wq[idx] * scale : wk[idx - 262144];
        Wqk[idx] = f2bf(v);
    }
    if (idx < 262144) {
        Wv[idx] = f2bf(wv[idx]);
        Wo[idx] = f2bf(wo[idx]);
    }
    if (idx < 1024) bqk[idx] = (idx < 512) ? bq[idx] * scale : bk[idx - 512];
    if (idx < 256) stats[idx] = 0.f;     // 128 x {sum, sumsq}
}

// ---- GN pass 1: partial sums, 8 blocks per (b,g) group ---------------------
__global__ __launch_bounds__(256) void gn_stats(
    const float* __restrict__ x, float* __restrict__ stats)
{
    int blk = blockIdx.x;               // 1024 = grp*8 + sub
    int grp = blk >> 3, sub = blk & 7;
    const float* xp = x + (size_t)grp * 65536 + sub * 8192;
    int tid = threadIdx.x;

    float s = 0.f, sq = 0.f;
    #pragma unroll
    for (int j = 0; j < 8; ++j) {
        float4 v = *(const float4*)&xp[tid * 4 + j * 1024];
        s  += v.x + v.y + v.z + v.w;
        sq += v.x * v.x + v.y * v.y + v.z * v.z + v.w * v.w;
    }
    #pragma unroll
    for (int off = 32; off; off >>= 1) {
        s  += __shfl_xor(s,  off, 64);
        sq += __shfl_xor(sq, off, 64);
    }
    __shared__ float red[8];
    if ((tid & 63) == 0) { red[(tid >> 6) * 2] = s; red[(tid >> 6) * 2 + 1] = sq; }
    __syncthreads();
    if (tid == 0) {
        atomicAdd(&stats[grp * 2],     red[0] + red[2] + red[4] + red[6]);
        atomicAdd(&stats[grp * 2 + 1], red[1] + red[3] + red[5] + red[7]);
    }
}

// ---- GN pass 2: normalize + transpose one 256-pixel tile -------------------
__global__ __launch_bounds__(256) void gn_apply(
    const float* __restrict__ x, const float* __restrict__ gamma,
    const float* __restrict__ beta, const float* __restrict__ stats,
    ushort* __restrict__ hnt)
{
    int blk = blockIdx.x;               // 2048 = grp*16 + tile
    int grp = blk >> 4, tile = blk & 15;
    int b = grp >> 5, g = grp & 31;
    const float* xp = x + (size_t)grp * 65536;
    int tid = threadIdx.x;

    float mean = stats[grp * 2] * (1.f / 65536.f);
    float var  = stats[grp * 2 + 1] * (1.f / 65536.f) - mean * mean;
    float rstd = rsqrtf(var + 1e-6f);

    int i0 = tile * 256;
    __shared__ ushort ls[16][256];
    #pragma unroll
    for (int ch = 0; ch < 16; ++ch) {
        float a = rstd * gamma[g * 16 + ch];
        float c = beta[g * 16 + ch] - mean * a;
        ls[ch][tid] = f2bf(xp[ch * 4096 + i0 + tid] * a + c);
    }
    __syncthreads();
    ushort t[16];
    #pragma unroll
    for (int ch = 0; ch < 16; ++ch) t[ch] = ls[ch][tid];
    size_t dst = ((size_t)b * 4096 + i0 + tid) * 512 + g * 16;
    *(uint4*)&hnt[dst]     = *(const uint4*)&t[0];
    *(uint4*)&hnt[dst + 8] = *(const uint4*)&t[8];
}

// ---- softmax: bf16 S in -> fp8 (x256) P8 out, K-INTERLEAVED layout ---------
// Within each 64-byte j-group, 8-byte pieces are stored in the order
// [j0-7 | j32-39 | j8-15 | j40-47 | j16-23 | j48-55 | j24-31 | j56-63]
// so the PV kernel can fragment-read with a single conflict-clean b128.
__global__ __launch_bounds__(256) void softmax_kernel(
    const ushort* __restrict__ S, unsigned char* __restrict__ P8)
{
    size_t row = blockIdx.x;
    const ushort* p = S + row * 4096;
    int tid = threadIdx.x;

    ushort tmp[16];
    *(uint4*)&tmp[0] = *(const uint4*)&p[tid * 16];
    *(uint4*)&tmp[8] = *(const uint4*)&p[tid * 16 + 8];
    float v[16];
    float mx = -1e30f;
    #pragma unroll
    for (int j = 0; j < 16; ++j) { v[j] = bf2f(tmp[j]); mx = fmaxf(mx, v[j]); }
    #pragma unroll
    for (int off = 32; off; off >>= 1) mx = fmaxf(mx, __shfl_xor(mx, off, 64));
    __shared__ float ls[8];
    if ((tid & 63) == 0) ls[tid >> 6] = mx;
    __syncthreads();
    float m4 = fmaxf(fmaxf(ls[0], ls[1]), fmaxf(ls[2], ls[3]));
    float sum = 0.f;
    #pragma unroll
    for (int j = 0; j < 16; ++j) { v[j] = __expf(v[j] - m4); sum += v[j]; }
    #pragma unroll
    for (int off = 32; off; off >>= 1) sum += __shfl_xor(sum, off, 64);
    if ((tid & 63) == 0) ls[4 + (tid >> 6)] = sum;
    __syncthreads();
    // scale by 256 so diffuse probs (~2.4e-4) clear e4m3's subnormal floor
    float inv = 256.0f / (ls[4] + ls[5] + ls[6] + ls[7]);
    int u = tid & 3;
    size_t base = row * 4096 + (size_t)(tid >> 2) * 64
                + (u & 1) * 32 + (u >> 1) * 8;
    uint2 o0, o1;
    o0.x = pk4_fp8(v[0] * inv,  v[1] * inv,  v[2] * inv,  v[3] * inv);
    o0.y = pk4_fp8(v[4] * inv,  v[5] * inv,  v[6] * inv,  v[7] * inv);
    o1.x = pk4_fp8(v[8] * inv,  v[9] * inv,  v[10] * inv, v[11] * inv);
    o1.y = pk4_fp8(v[12] * inv, v[13] * inv, v[14] * inv, v[15] * inv);
    *(uint2*)&P8[base]      = o0;
    *(uint2*)&P8[base + 16] = o1;
}

// ---- NT bf16 MFMA GEMM, 128x128 tile, BK=64 (two 32-k sub-tiles/barrier) ---
// C[m,n] = sum_k A[m,k]*B[n,k]   A: [M][K] lda, B: [N][K] ldb (both K-contig)
// OUT: 0 bf16, 1 fp32 + resid, 2 fp8 K-interleaved, 3 split Q/K fp8 (Q x16).
// BIAS: 0 none, 1 row, 2 col.
template <int BIAS, int OUT>
__global__ __launch_bounds__(256, 4) void gemm_nt(
    const ushort* __restrict__ Ag, const ushort* __restrict__ Bg,
    void* __restrict__ Cv, void* __restrict__ Cv2,
    const float* __restrict__ bias, const float* __restrict__ resid,
    int N, int K, int lda, int ldb,
    long sA, long sB, long sC)
{
    const int bz = blockIdx.z;
    Ag += (size_t)bz * sA;
    Bg += (size_t)bz * sB;

    const int tid  = threadIdx.x;
    const int wave = tid >> 6, lane = tid & 63;
    const int q = lane >> 4, lr = lane & 15;
    const int m0 = blockIdx.x * 128, n0 = blockIdx.y * 128;   // m on X!
    const int wm = (wave >> 1) * 64, wn = (wave & 1) * 64;

    __shared__ __align__(16) ushort As[2][128 * 32];   // 2 x 8 KB
    __shared__ __align__(16) ushort Bs[2][128 * 32];   // 2 x 8 KB

    const int srow = wave * 32 + (lane >> 2);
    const int skc  = (lane & 3) << 3;
    const size_t aoff0 = (size_t)(m0 + srow) * lda + skc;
    const size_t aoff1 = aoff0 + (size_t)16 * lda;
    const size_t boff0 = (size_t)(n0 + srow) * ldb + skc;
    const size_t boff1 = boff0 + (size_t)16 * ldb;
    const int l0 = wave * 1024, l1 = wave * 1024 + 512;   // wave-uniform bases

    f32x4 acc[4][4] = {};

    for (int kb = 0; kb < K; kb += 64) {
        __syncthreads();
        gload16(&Ag[aoff0 + kb],      &As[0][l0]);
        gload16(&Ag[aoff1 + kb],      &As[0][l1]);
        gload16(&Ag[aoff0 + kb + 32], &As[1][l0]);
        gload16(&Ag[aoff1 + kb + 32], &As[1][l1]);
        gload16(&Bg[boff0 + kb],      &Bs[0][l0]);
        gload16(&Bg[boff1 + kb],      &Bs[0][l1]);
        gload16(&Bg[boff0 + kb + 32], &Bs[1][l0]);
        gload16(&Bg[boff1 + kb + 32], &Bs[1][l1]);
        __syncthreads();

        #pragma unroll
        for (int kh = 0; kh < 2; ++kh) {
            short8 af[4], bfr[4];
            #pragma unroll
            for (int mt = 0; mt < 4; ++mt)
                af[mt] = *(const short8*)&As[kh][(wm + mt * 16 + lr) * 32 + q * 8];
            #pragma unroll
            for (int nt = 0; nt < 4; ++nt)
                bfr[nt] = *(const short8*)&Bs[kh][(wn + nt * 16 + lr) * 32 + q * 8];
            #pragma unroll
            for (int mt = 0; mt < 4; ++mt)
                #pragma unroll
                for (int nt = 0; nt < 4; ++nt)
                    acc[mt][nt] = __builtin_amdgcn_mfma_f32_16x16x32_bf16(
                        af[mt], bfr[nt], acc[mt][nt], 0, 0, 0);
        }
    }

    #pragma unroll
    for (int mt = 0; mt < 4; ++mt) {
        int rb = m0 + wm + mt * 16 + q * 4;
        #pragma unroll
        for (int nt = 0; nt < 4; ++nt) {
            int cn = n0 + wn + nt * 16 + lr;
            #pragma unroll
            for (int t = 0; t < 4; ++t) {
                int r = rb + t;
                float v = acc[mt][nt][t];
                if (BIAS == 1) v += bias[r];
                if (BIAS == 2) v += bias[cn];
                if (OUT == 1) {
                    size_t o = (size_t)bz * sC + (size_t)r * N + cn;
                    ((float*)Cv)[o] = v + resid[o];
                } else if (OUT == 2) {
                    // K-interleave the column index within its 64-group
                    int w = cn & 63, a = w >> 3;
                    int sp = (cn & ~63) | ((a & 3) * 16 + (a >> 2) * 8 + (w & 7));
                    ((unsigned char*)Cv)[(size_t)bz * sC + (size_t)r * N + sp] =
                        f2fp8(v);
                } else if (OUT == 3) {
                    // split 1024-wide output: cols [0,512) -> Q8 (x16),
                    // cols [512,1024) -> K8. sC = per-batch elems of each.
                    if (cn < 512)
                        ((unsigned char*)Cv)[(size_t)bz * sC + (size_t)r * 512 + cn]
                            = f2fp8(v * 16.f);
                    else
                        ((unsigned char*)Cv2)[(size_t)bz * sC + (size_t)r * 512 + (cn - 512)]
                            = f2fp8(v);
                } else {
                    size_t o = (size_t)bz * sC + (size_t)r * N + cn;
                    ((ushort*)Cv)[o] = f2bf(v);
                }
            }
        }
    }
}

// ---- scores GEMM, MX-fp8 (K=128 scaled MFMA), 128x128 tile -----------------
// S[i][j] = sum_c Q8[i,c]*2^-4 * K8[j,c].  M=N=4096, K=512 bytes, 4 K-iters.
// LDS rows are 128 B with XOR-swizzled 16B pieces: slot p of row r holds
// global piece p^(r&7), realized by permuting each lane's GLOBAL source
// (dest stays wave-uniform + lane*16). Fragment reads then hit all 32 banks
// at 2 lanes/bank (free).
__global__ __launch_bounds__(256, 2) void gemm_qk(
    const unsigned char* __restrict__ Q8, const unsigned char* __restrict__ K8,
    ushort* __restrict__ S)
{
    const int bz = blockIdx.z;
    const unsigned char* Ag = Q8 + (size_t)bz * 2097152;   // 4096*512
    const unsigned char* Bg = K8 + (size_t)bz * 2097152;

    const int tid  = threadIdx.x;
    const int wave = tid >> 6, lane = tid & 63;
    const int q = lane >> 4, lr = lane & 15;
    const int m0 = blockIdx.x * 128, n0 = blockIdx.y * 128;
    const int wm = (wave >> 1) * 64, wn = (wave & 1) * 64;

    __shared__ __align__(16) unsigned char As[128 * 128];   // 16 KB
    __shared__ __align__(16) unsigned char Bs[128 * 128];   // 16 KB

    // staging: lane i covers local row i>>3, swizzled piece (i&7)^((i>>3)&7)
    const int lrow = lane >> 3;
    const size_t laneoff = (size_t)lrow * 512 + ((lane & 7) ^ (lrow & 7)) * 16;
    const size_t abase = (size_t)(m0 + wave * 32) * 512 + laneoff;
    const size_t bbase = (size_t)(n0 + wave * 32) * 512 + laneoff;
    unsigned char* lA = &As[wave * 32 * 128];   // wave-uniform
    unsigned char* lB = &Bs[wave * 32 * 128];

    // fragment read swizzle: row&7 == lr&7 for all tiles (offsets mult of 8)
    const int e0 = (2 * q) ^ (lr & 7), e1 = e0 ^ 1;

    f32x4 acc[4][4] = {};
    const int sA = 0x7B7B7B7B;   // e8m0 2^-4 (undo the x16 in Q8)
    const int sB = 0x7F7F7F7F;   // e8m0 1.0

    for (int kb = 0; kb < 512; kb += 128) {
        __syncthreads();
        #pragma unroll
        for (int t = 0; t < 4; ++t) {
            gload16(Ag + abase + (size_t)t * 4096 + kb, lA + t * 1024);
            gload16(Bg + bbase + (size_t)t * 4096 + kb, lB + t * 1024);
        }
        __syncthreads();

        i32x8 af[4], bf[4];
        #pragma unroll
        for (int mt = 0; mt < 4; ++mt) {
            int r = wm + mt * 16 + lr;
            union { uint4 v[2]; i32x8 f; } u;
            u.v[0] = *(const uint4*)&As[r * 128 + e0 * 16];
            u.v[1] = *(const uint4*)&As[r * 128 + e1 * 16];
            af[mt] = u.f;
        }
        #pragma unroll
        for (int nt = 0; nt < 4; ++nt) {
            int r = wn + nt * 16 + lr;
            union { uint4 v[2]; i32x8 f; } u;
            u.v[0] = *(const uint4*)&Bs[r * 128 + e0 * 16];
            u.v[1] = *(const uint4*)&Bs[r * 128 + e1 * 16];
            bf[nt] = u.f;
        }
        #pragma unroll
        for (int mt = 0; mt < 4; ++mt)
            #pragma unroll
            for (int nt = 0; nt < 4; ++nt)
                acc[mt][nt] = __builtin_amdgcn_mfma_scale_f32_16x16x128_f8f6f4(
                    af[mt], bf[nt], acc[mt][nt], 0, 0, 0, sA, 0, sB);
    }

    #pragma unroll
    for (int mt = 0; mt < 4; ++mt) {
        int rb = m0 + wm + mt * 16 + q * 4;
        #pragma unroll
        for (int nt = 0; nt < 4; ++nt) {
            int cn = n0 + wn + nt * 16 + lr;
            #pragma unroll
            for (int t = 0; t < 4; ++t) {
                size_t o = (size_t)bz * 16777216 + (size_t)(rb + t) * 4096 + cn;
                S[o] = f2bf(acc[mt][nt][t]);
            }
        }
    }
}

// ---- PV GEMM, fp8 e4m3, 128x128 tile, BK=128 fp8 elems per barrier ---------
__global__ __launch_bounds__(256, 4) void gemm_pv(
    const unsigned char* __restrict__ P8, const unsigned char* __restrict__ V8,
    ushort* __restrict__ Ot)
{
    const int bz = blockIdx.z;
    const unsigned char* Ag = P8 + (size_t)bz * 16777216;   // 4096*4096
    const unsigned char* Bg = V8 + (size_t)bz * 2097152;    // 512*4096

    const int tid  = threadIdx.x;
    const int wave = tid >> 6, lane = tid & 63;
    const int q = lane >> 4, lr = lane & 15;
    const int m0 = blockIdx.x * 128, n0 = blockIdx.y * 128;  // m on X (XCD share)
    const int wm = (wave >> 1) * 64, wn = (wave & 1) * 64;

    __shared__ __align__(16) unsigned char As[2][128 * 64];  // 2 x 8 KB
    __shared__ __align__(16) unsigned char Bs[2][128 * 64];  // 2 x 8 KB

    const int srow = wave * 32 + (lane >> 2);
    const int soff = (lane & 3) << 4;               // 16-B chunk in 64-B row
    const size_t a0 = (size_t)(m0 + srow) * 4096 + soff;
    const size_t a1 = a0 + (size_t)16 * 4096;
    const size_t b0 = (size_t)(n0 + srow) * 4096 + soff;
    const size_t b1 = b0 + (size_t)16 * 4096;
    const int l0 = wave * 2048, l1 = wave * 2048 + 1024;

    f32x4 acc[4][4] = {};

    for (int kb = 0; kb < 4096; kb += 128) {
        __syncthreads();
        gload16(Ag + a0 + kb,      &As[0][l0]);
        gload16(Ag + a1 + kb,      &As[0][l1]);
        gload16(Ag + a0 + kb + 64, &As[1][l0]);
        gload16(Ag + a1 + kb + 64, &As[1][l1]);
        gload16(Bg + b0 + kb,      &Bs[0][l0]);
        gload16(Bg + b1 + kb,      &Bs[0][l1]);
        gload16(Bg + b0 + kb + 64, &Bs[1][l0]);
        gload16(Bg + b1 + kb + 64, &Bs[1][l1]);
        __syncthreads();

        #pragma unroll
        for (int kh = 0; kh < 2; ++kh) {
            llong2 af[4], bf[4];
            #pragma unroll
            for (int mt = 0; mt < 4; ++mt)
                af[mt] = *(const llong2*)
                    &As[kh][(wm + mt * 16 + lr) * 64 + q * 16];
            #pragma unroll
            for (int nt = 0; nt < 4; ++nt)
                bf[nt] = *(const llong2*)
                    &Bs[kh][(wn + nt * 16 + lr) * 64 + q * 16];
            #pragma unroll
            for (int mt = 0; mt < 4; ++mt)
                #pragma unroll
                for (int nt = 0; nt < 4; ++nt)
                    acc[mt][nt] = __builtin_amdgcn_mfma_f32_16x16x32_fp8_fp8(
                        af[mt].x, bf[nt].x, acc[mt][nt], 0, 0, 0);
            #pragma unroll
            for (int mt = 0; mt < 4; ++mt)
                #pragma unroll
                for (int nt = 0; nt < 4; ++nt)
                    acc[mt][nt] = __builtin_amdgcn_mfma_f32_16x16x32_fp8_fp8(
                        af[mt].y, bf[nt].y, acc[mt][nt], 0, 0, 0);
        }
    }

    #pragma unroll
    for (int mt = 0; mt < 4; ++mt) {
        int rb = m0 + wm + mt * 16 + q * 4;
        #pragma unroll
        for (int nt = 0; nt < 4; ++nt) {
            int cn = n0 + wn + nt * 16 + lr;
            #pragma unroll
            for (int t = 0; t < 4; ++t) {
                size_t o = (size_t)bz * 2097152 + (size_t)(rb + t) * 512 + cn;
                Ot[o] = f2bf(acc[mt][nt][t] * (1.f / 256.f));
            }
        }
    }
}

// ---------------- launch -----------------------------------------------------
extern "C" void kernel_launch(void* const* d_in, const int* in_sizes, int n_in,
                              void* d_out, int out_size, void* d_ws, size_t ws_size,
                              hipStream_t stream)
{
    const float* x   = (const float*)d_in[0];
    const float* gnw = (const float*)d_in[1];
    const float* gnb = (const float*)d_in[2];
    const float* wq  = (const float*)d_in[3];
    const float* bq  = (const float*)d_in[4];
    const float* wk  = (const float*)d_in[5];
    const float* bk  = (const float*)d_in[6];
    const float* wv  = (const float*)d_in[7];
    const float* bv  = (const float*)d_in[8];
    const float* wo  = (const float*)d_in[9];
    const float* bo  = (const float*)d_in[10];
    float* out = (float*)d_out;

    char* ws = (char*)d_ws;
    // ws layout with lifetime overlays (~212 MB):
    //  [0,128M)      S (bf16 scores)  -> dead after softmax; Ot overlays [0,16M)
    //  [128M,144M)   hnt              -> dead after projections
    //  [144M,152M)   Q8, [152M,160M) K8 -> dead after scores
    //  [128M,192M)   P8 (fp8 x256)    -> overlay, written by softmax
    //  [192M,200M)   V8 (fp8)
    //  [200M+..]     weights | bqk | gn stats
    ushort*        S   = (ushort*)(ws);
    ushort*        Ot  = (ushort*)(ws);                       // overlay of S
    ushort*        hnt = (ushort*)(ws + 134217728);
    unsigned char* Q8  = (unsigned char*)(ws + 150994944);
    unsigned char* K8  = (unsigned char*)(ws + 159383552);
    unsigned char* P8  = (unsigned char*)(ws + 134217728);    // overlay
    unsigned char* V8  = (unsigned char*)(ws + 201326592);
    ushort*        Wqk = (ushort*)(ws + 209715200);
    ushort*        Wv  = (ushort*)(ws + 210763776);
    ushort*        Wo  = (ushort*)(ws + 211288064);
    float*         bqk = (float*) (ws + 211812352);
    float*         st  = (float*) (ws + 211816448);           // 128 x {s,sq}

    const float scale = 1.0f / sqrtf(512.0f);
    const long sHW  = 512L * 4096;     // 2 M elems

    prep_weights<<<2048, 256, 0, stream>>>(wq, bq, wk, bk, wv, wo,
                                           Wqk, Wv, Wo, bqk, st, scale);
    gn_stats<<<1024, 256, 0, stream>>>(x, st);
    gn_apply<<<2048, 256, 0, stream>>>(x, gnw, gnb, st, hnt);

    // Q8[i][c]=fp8(16*q), K8[j][c]=fp8(k)  (M=4096, N=1024, K=512), col-bias
    gemm_nt<2, 3><<<dim3(32, 8, 4), 256, 0, stream>>>(
        hnt, Wqk, Q8, K8, bqk, nullptr,
        1024, 512, 512, 512, sHW, 0L, sHW);

    // V8[o][j] = fp8( Wv[o][c] . hn_t[j][c] + bv ), K-interleaved
    gemm_nt<1, 2><<<dim3(4, 32, 4), 256, 0, stream>>>(
        Wv, hnt, V8, nullptr, bv, nullptr,
        4096, 512, 512, 512, 0L, sHW, sHW);

    // S[i][j] = (Q8*2^-4).K8  (MX fp8 MFMA, K=128/inst, 4 K-iters)
    gemm_qk<<<dim3(32, 32, 4), 256, 0, stream>>>(Q8, K8, S);

    softmax_kernel<<<16384, 256, 0, stream>>>(S, P8);

    // Ot[i][c] = (1/256) P8[i][j] . V8[c][j]  (fp8 MFMA, BK=128)
    gemm_pv<<<dim3(32, 4, 4), 256, 0, stream>>>(P8, V8, Ot);

    // out[o][i] = x + Wo[o][c] . Ot[i][c] + bo  (M=512, N=4096, K=512), fp32
    gemm_nt<1, 1><<<dim3(4, 32, 4), 256, 0, stream>>>(
        Wo, Ot, out, nullptr, bo, x,
        4096, 512, 512, 512, 0L, sHW, sHW);
}